// Round 16
// baseline (165.168 us; speedup 1.0000x reference)
//
#include <hip/hip_runtime.h>
#include <math.h>

#define LNUM 3
#define ENUM 8
#define TOPK 2
#define BSZ 256
#define NSZ 1024
#define DSZ 512
#define SSZ 128   // DS

typedef float f32x4 __attribute__((ext_vector_type(4)));

// ---------------- mega kernel: 3 layers + q + logits, block b owns token b ----------------
// grid = BSZ blocks, 1024 threads (16 waves). h lives in LDS across layers;
// q never leaves LDS; each block streams its own node_emb slice for logits.
// Experts sequential (R10/R14: beats concurrent). LDS-partial combines with
// column idx in LOW lane bits (R12: K-in-low-bits destroys coalescing).
// Wg staged through LDS (R13: direct strided read costs +10us).
__global__ __launch_bounds__(1024, 2) void mega_kernel(
    const float* __restrict__ token,   // [B][D]
    const float* __restrict__ node_emb,// [B][N][D]
    const float* __restrict__ states,  // [L][E][B][DS]
    const float* __restrict__ Wg,      // [L][D][E]
    const float* __restrict__ bg,      // [L][E]
    const float* __restrict__ A,       // [L][E][DS]
    const float* __restrict__ Bin,     // [L][E][D][DS]
    const float* __restrict__ Cout,    // [L][E][DS][D]
    const float* __restrict__ Dsk,     // [L][E][D]
    const float* __restrict__ Wq,      // [D][D]
    const float* __restrict__ bq,      // [D]
    float* __restrict__ out_logits,    // [B][N]
    float* __restrict__ out_states,    // [L][E][B][DS]
    float* __restrict__ acc)           // [L][2][E] (probs, sel) — pre-zeroed
{
    const int b = blockIdx.x;
    const int t = threadIdx.x;
    const int wave = t >> 6;
    const int lane = t & 63;

    __shared__ float h_s[DSZ];
    __shared__ float yacc_s[DSZ];      // also q_s in the logits phase
    __shared__ float snew_s[TOPK][SSZ];
    __shared__ float logit_s[ENUM];
    __shared__ f32x4 part4[1024];      // 16 KB scratch, reused every phase
    float* part = (float*)part4;

    if (t < 128) ((f32x4*)h_s)[t] = ((const f32x4*)(token + (size_t)b * DSZ))[t];

    for (int l = 0; l < LNUM; ++l) {
        const float* Wg_l  = Wg  + (size_t)l * DSZ * ENUM;
        const float* bg_l  = bg  + (size_t)l * ENUM;
        const float* A_l   = A   + (size_t)l * ENUM * SSZ;
        const float* Bin_l = Bin + (size_t)l * ENUM * DSZ * SSZ;
        const float* Cou_l = Cout+ (size_t)l * ENUM * SSZ * DSZ;
        const float* Dsk_l = Dsk + (size_t)l * ENUM * DSZ;
        const float* st_l  = states     + (size_t)l * ENUM * BSZ * SSZ;
        float*       os_l  = out_states + (size_t)l * ENUM * BSZ * SSZ;

        // stage Wg[l] (16 KB) into part; also fences h_s (init load / l-1 update)
        __syncthreads();
        part4[t] = ((const f32x4*)Wg_l)[t];
        __syncthreads();

        // gating logits: wave w computes expert w from staged Wg
        if (wave < ENUM) {
            float p = 0.f;
            #pragma unroll
            for (int i = 0; i < 8; ++i) {
                const int d = lane + i * 64;
                p = fmaf(h_s[d], part[d * ENUM + wave], p);
            }
            for (int off = 32; off; off >>= 1) p += __shfl_down(p, off, 64);
            if (lane == 0) logit_s[wave] = p + bg_l[wave];
        }
        __syncthreads();

        // softmax + top2, redundantly per thread (identical results)
        float probs[ENUM];
        float mx = logit_s[0];
        for (int e = 1; e < ENUM; ++e) mx = fmaxf(mx, logit_s[e]);
        float ssum = 0.f;
        for (int e = 0; e < ENUM; ++e) { probs[e] = expf(logit_s[e] - mx); ssum += probs[e]; }
        const float sinv = 1.f / ssum;
        for (int e = 0; e < ENUM; ++e) probs[e] *= sinv;

        int i0 = 0;
        for (int e = 1; e < ENUM; ++e) if (probs[e] > probs[i0]) i0 = e;
        int i1 = -1;
        for (int e = 0; e < ENUM; ++e) {
            if (e == i0) continue;
            if (i1 < 0 || probs[e] > probs[i1]) i1 = e;
        }
        float g0 = probs[i0], g1 = probs[i1];
        const float ginv = 1.f / (g0 + g1);
        g0 *= ginv; g1 *= ginv;

        if (t < ENUM) {
            atomicAdd(&acc[(l * 2 + 0) * ENUM + t], probs[t]);
            atomicAdd(&acc[(l * 2 + 1) * ENUM + t], (t == i0 || t == i1) ? 1.0f : 0.0f);
        }

        // ---- s_new: experts sequentially, all 1024 threads each ----
        #pragma unroll
        for (int k = 0; k < TOPK; ++k) {
            const int e = k ? i1 : i0;
            {
                const int c  = t >> 5;     // 0..31, K-chunk of 16 (HIGH bits)
                const int sq = t & 31;     // s-quad (LOW bits -> coalesced)
                const float* Bp = Bin_l + (size_t)e * DSZ * SSZ + sq * 4;
                const int d0 = c * 16;
                f32x4 acc4 = {0.f, 0.f, 0.f, 0.f};
                #pragma unroll
                for (int d = 0; d < 16; ++d)
                    acc4 += *(const f32x4*)(Bp + (size_t)(d0 + d) * SSZ) * h_s[d0 + d];
                part4[c * 32 + sq] = acc4;
            }
            __syncthreads();
            if (t < SSZ) {
                float sum = 0.f;
                #pragma unroll
                for (int c = 0; c < 32; ++c) sum += part[c * 128 + t];
                const float a = A_l[e * SSZ + t];
                const float decay = 1.f / (1.f + expf(-a));
                snew_s[k][t] = decay * st_l[((size_t)e * BSZ + b) * SSZ + t] + sum;
            }
            __syncthreads();
        }

        // write new_states for all 8 experts (1 elem/thread)
        {
            const int e = t >> 7, s = t & 127;
            float v;
            if (e == i0)      v = snew_s[0][s];
            else if (e == i1) v = snew_s[1][s];
            else              v = st_l[((size_t)e * BSZ + b) * SSZ + s];
            os_l[((size_t)e * BSZ + b) * SSZ + s] = v;
        }

        // ---- y: experts sequentially, all 1024 threads each ----
        #pragma unroll
        for (int k = 0; k < TOPK; ++k) {
            const int e = k ? i1 : i0;
            const float g = k ? g1 : g0;
            {
                const int sc = t >> 7;     // 0..7, S-chunk of 16 (HIGH bits)
                const int dq = t & 127;    // d-quad (LOW bits -> coalesced)
                const float* Cp = Cou_l + (size_t)e * SSZ * DSZ + dq * 4;
                const float* sp = snew_s[k];
                const int s0 = sc * 16;
                f32x4 acc4 = {0.f, 0.f, 0.f, 0.f};
                #pragma unroll
                for (int s = 0; s < 16; ++s)
                    acc4 += *(const f32x4*)(Cp + (size_t)(s0 + s) * DSZ) * sp[s0 + s];
                part4[sc * 128 + dq] = acc4;
            }
            __syncthreads();
            if (t < DSZ) {
                float yk = 0.f;
                #pragma unroll
                for (int sc = 0; sc < 8; ++sc) yk += part[sc * 512 + t];
                const float hd = h_s[t];
                yk = g * (yk + hd * Dsk_l[e * DSZ + t]);
                if (k == 0) yacc_s[t] = yk;
                else        h_s[t] = hd + yacc_s[t] + yk;
            }
            __syncthreads();
        }
    }

    // ---- q = h @ Wq + bq -> yacc_s (stays in LDS) ----
    {
        const int chunk = t >> 7;        // 0..7, dd-chunk of 64
        const int dquad = t & 127;
        const int dd0 = chunk * 64;
        f32x4 acc4 = {0.f, 0.f, 0.f, 0.f};
        #pragma unroll 8
        for (int i = 0; i < 64; ++i)
            acc4 += *(const f32x4*)(Wq + (size_t)(dd0 + i) * DSZ + dquad * 4) * h_s[dd0 + i];
        part4[chunk * 128 + dquad] = acc4;
    }
    __syncthreads();
    if (t < DSZ) {
        float qv = bq[t];
        #pragma unroll
        for (int c = 0; c < 8; ++c) qv += part[c * 512 + t];
        yacc_s[t] = qv;
    }
    __syncthreads();

    // ---- logits: wave w streams rows w*64 .. w*64+63 of node_emb[b] ----
    // 4-row ILP: 8 loads in flight, 4 independent accumulators, then 4 reduces.
    {
        const f32x4 q0 = ((const f32x4*)yacc_s)[lane];
        const f32x4 q1 = ((const f32x4*)yacc_s)[lane + 64];
        const float scale = 0.04419417382415922f;  // 1/sqrt(512)
        const int n0 = wave * 64;
        for (int i = 0; i < 64; i += 4) {
            const f32x4* r0 = (const f32x4*)(node_emb + ((size_t)b * NSZ + n0 + i) * DSZ);
            const f32x4* r1 = (const f32x4*)(node_emb + ((size_t)b * NSZ + n0 + i + 1) * DSZ);
            const f32x4* r2 = (const f32x4*)(node_emb + ((size_t)b * NSZ + n0 + i + 2) * DSZ);
            const f32x4* r3 = (const f32x4*)(node_emb + ((size_t)b * NSZ + n0 + i + 3) * DSZ);
            const f32x4 a00 = __builtin_nontemporal_load(r0 + lane);
            const f32x4 a01 = __builtin_nontemporal_load(r0 + lane + 64);
            const f32x4 a10 = __builtin_nontemporal_load(r1 + lane);
            const f32x4 a11 = __builtin_nontemporal_load(r1 + lane + 64);
            const f32x4 a20 = __builtin_nontemporal_load(r2 + lane);
            const f32x4 a21 = __builtin_nontemporal_load(r2 + lane + 64);
            const f32x4 a30 = __builtin_nontemporal_load(r3 + lane);
            const f32x4 a31 = __builtin_nontemporal_load(r3 + lane + 64);
            float d0 = a00.x*q0.x + a00.y*q0.y + a00.z*q0.z + a00.w*q0.w
                     + a01.x*q1.x + a01.y*q1.y + a01.z*q1.z + a01.w*q1.w;
            float d1 = a10.x*q0.x + a10.y*q0.y + a10.z*q0.z + a10.w*q0.w
                     + a11.x*q1.x + a11.y*q1.y + a11.z*q1.z + a11.w*q1.w;
            float d2 = a20.x*q0.x + a20.y*q0.y + a20.z*q0.z + a20.w*q0.w
                     + a21.x*q1.x + a21.y*q1.y + a21.z*q1.z + a21.w*q1.w;
            float d3 = a30.x*q0.x + a30.y*q0.y + a30.z*q0.z + a30.w*q0.w
                     + a31.x*q1.x + a31.y*q1.y + a31.z*q1.z + a31.w*q1.w;
            #pragma unroll
            for (int off = 32; off; off >>= 1) {
                d0 += __shfl_down(d0, off, 64);
                d1 += __shfl_down(d1, off, 64);
                d2 += __shfl_down(d2, off, 64);
                d3 += __shfl_down(d3, off, 64);
            }
            if (lane == 0) {
                out_logits[b * NSZ + n0 + i]     = d0 * scale;
                out_logits[b * NSZ + n0 + i + 1] = d1 * scale;
                out_logits[b * NSZ + n0 + i + 2] = d2 * scale;
                out_logits[b * NSZ + n0 + i + 3] = d3 * scale;
            }
        }
    }
}

// ---------------- lb_loss finisher ----------------
__global__ void loss_kernel(const float* __restrict__ acc, float* __restrict__ out)
{
    if (threadIdx.x == 0) {
        float lb = 0.f;
        for (int l = 0; l < LNUM; ++l)
            for (int e = 0; e < ENUM; ++e) {
                const float mp = acc[(l * 2 + 0) * ENUM + e] * (1.0f / BSZ);
                const float ms = acc[(l * 2 + 1) * ENUM + e] * (1.0f / BSZ);
                lb += (float)ENUM * mp * ms;
            }
        out[0] = lb;
    }
}

extern "C" void kernel_launch(void* const* d_in, const int* in_sizes, int n_in,
                              void* d_out, int out_size, void* d_ws, size_t ws_size,
                              hipStream_t stream) {
    const float* token    = (const float*)d_in[0];  // B,1,D
    const float* node_emb = (const float*)d_in[1];  // B,N,D
    const float* states   = (const float*)d_in[2];  // L,E,B,DS
    const float* Wg       = (const float*)d_in[3];  // L,D,E
    const float* bg       = (const float*)d_in[4];  // L,E
    const float* A        = (const float*)d_in[5];  // L,E,DS
    const float* Bin      = (const float*)d_in[6];  // L,E,D,DS
    const float* Cout     = (const float*)d_in[7];  // L,E,DS,D
    const float* Dsk      = (const float*)d_in[8];  // L,E,D
    const float* Wq       = (const float*)d_in[9];  // D,D
    const float* bq       = (const float*)d_in[10]; // D

    float* out_logits = (float*)d_out;                                  // B*N
    float* out_states = out_logits + (size_t)BSZ * NSZ;                 // L*E*B*DS
    float* out_loss   = out_states + (size_t)LNUM * ENUM * BSZ * SSZ;   // 1

    float* ws_acc = (float*)d_ws;   // 48 floats

    (void)hipMemsetAsync(ws_acc, 0, sizeof(float) * LNUM * 16, stream);

    mega_kernel<<<BSZ, 1024, 0, stream>>>(
        token, node_emb, states, Wg, bg, A, Bin, Cout, Dsk, Wq, bq,
        out_logits, out_states, ws_acc);

    loss_kernel<<<1, 64, 0, stream>>>(ws_acc, out_loss);
}